// Round 2
// baseline (19.807 us; speedup 1.0000x reference)
//
#include <hip/hip_runtime.h>
#include <math.h>

// 2-qubit circuit: output is identical for every batch element (x only sets B).
// Compute the 17 complex values once (thread 0), broadcast-write with float4.

struct C2 { double r, i; };

__device__ inline void rx_apply(C2 (&T)[4][2], int D, double th) {
    double c = cos(th * 0.5), s = sin(th * 0.5);
    for (int d = 0; d < D; ++d) {
        C2 a = T[d][0], b = T[d][1];
        // M = [[c, -i s], [-i s, c]]
        T[d][0] = { c * a.r + s * b.i,  c * a.i - s * b.r };
        T[d][1] = { s * a.i + c * b.r, -s * a.r + c * b.i };
    }
}

__device__ inline void entangle2(C2 (&T0)[4][2], C2 (&T1)[4][2], int D) {
    for (int d = 0; d < D; ++d) {
        T0[D + d][0] = {0.0, 0.0};
        T0[D + d][1] = T0[d][1];
        T1[D + d][0] = T1[d][1];
        T1[D + d][1] = T1[d][0];
        T0[d][1] = {0.0, 0.0};
    }
}

// Harness normalizes f64 inputs to f32; fall back to f64 read if the f32
// interpretation looks insane (f64 pi's low word reads as 3.4e12 in f32).
__device__ inline void load_w(const void* p, double& a, double& b) {
    const float* f = (const float*)p;
    float f0 = f[0], f1 = f[1];
    bool sane = isfinite(f0) && isfinite(f1) && fabsf(f0) < 1e5f && fabsf(f1) < 1e5f;
    if (sane) { a = (double)f0; b = (double)f1; }
    else      { const double* d = (const double*)p; a = d[0]; b = d[1]; }
}

__global__ __launch_bounds__(256) void qsim_bcast(
        const void* __restrict__ w1p, const void* __restrict__ w2p,
        float* __restrict__ out, long long n4A, long long n4B, int F) {
    __shared__ float4 tbl[8];   // state pattern (4 float4s if F==1, 8 if F==2)
    __shared__ float4 otblS;    // O pattern

    if (threadIdx.x == 0) {
        double w1a, w1b, w2a, w2b;
        load_w(w1p, w1a, w1b);
        load_w(w2p, w2a, w2b);

        C2 T0[4][2], T1[4][2];
        for (int d = 0; d < 4; ++d)
            for (int j = 0; j < 2; ++j) { T0[d][j] = {0.0, 0.0}; T1[d][j] = {0.0, 0.0}; }
        T0[0][0] = {1.0, 0.0};
        T1[0][0] = {1.0, 0.0};

        rx_apply(T0, 1, w1a);
        rx_apply(T1, 1, w1b);
        entangle2(T0, T1, 1);
        rx_apply(T0, 2, w2a);
        rx_apply(T1, 2, w2b);
        entangle2(T0, T1, 2);

        // psi[i][j] = sum_d T0[d][i]*T1[d][j];  O = sum zz_ij |psi_ij|^2 (real)
        double O = 0.0;
        const double zz[4] = {1.0, -1.0, -1.0, 1.0};
        for (int i2 = 0; i2 < 2; ++i2)
            for (int j2 = 0; j2 < 2; ++j2) {
                double pr = 0.0, pi = 0.0;
                for (int d = 0; d < 4; ++d) {
                    pr += T0[d][i2].r * T1[d][j2].r - T0[d][i2].i * T1[d][j2].i;
                    pi += T0[d][i2].r * T1[d][j2].i + T0[d][i2].i * T1[d][j2].r;
                }
                O += zz[i2 * 2 + j2] * (pr * pr + pi * pi);
            }

        // state flat order per batch: k = q*8 + d*2 + j  (16 complex values)
        float sv[32];  // interleaved re, im
        for (int d = 0; d < 4; ++d)
            for (int j = 0; j < 2; ++j) {
                int k0 = d * 2 + j;        // qubit 0
                int k1 = 8 + d * 2 + j;    // qubit 1
                sv[2 * k0]     = (float)T0[d][j].r;
                sv[2 * k0 + 1] = (float)T0[d][j].i;
                sv[2 * k1]     = (float)T1[d][j].r;
                sv[2 * k1 + 1] = (float)T1[d][j].i;
            }
        float Of = (float)O;

        if (F == 1) {
            // real parts only: float f = Re(cplx[f%16]); tbl[p] covers floats 4p..4p+3
            for (int p = 0; p < 4; ++p)
                tbl[p] = make_float4(sv[8 * p + 0], sv[8 * p + 2], sv[8 * p + 4], sv[8 * p + 6]);
            otblS = make_float4(Of, Of, Of, Of);
        } else {
            // interleaved re/im: float f = sv[f%32]
            for (int p = 0; p < 8; ++p)
                tbl[p] = make_float4(sv[4 * p + 0], sv[4 * p + 1], sv[4 * p + 2], sv[4 * p + 3]);
            otblS = make_float4(Of, 0.0f, Of, 0.0f);
        }
    }
    __syncthreads();

    const int mask = 4 * F - 1;
    const long long total = n4A + n4B;
    float4* __restrict__ o4 = (float4*)out;
    const long long i0 = (long long)blockIdx.x * blockDim.x + threadIdx.x;
    const long long step = (long long)gridDim.x * blockDim.x;
    // step (524288) is a multiple of 8 float4s -> pattern index is loop-invariant
    const float4 va = tbl[(int)(i0 & mask)];
    const float4 vo = otblS;
    for (long long i = i0; i < total; i += step) {
        o4[i] = (i < n4A) ? va : vo;
    }
}

extern "C" void kernel_launch(void* const* d_in, const int* in_sizes, int n_in,
                              void* d_out, int out_size, void* d_ws, size_t ws_size,
                              hipStream_t stream) {
    const long long Bn = in_sizes[0];  // 500000 (x is (B,1))

    // Output = (state: B*16 cplx, O: B cplx), concatenated flat as float32.
    // F==1: real parts only  -> out_size = 17*B
    // F==2: re/im interleaved -> out_size = 34*B
    const int F = ((long long)out_size >= Bn * 34LL) ? 2 : 1;

    const long long n4A = Bn * 4LL * F;   // state region in float4s
    const long long n4B = (Bn * F) / 4LL; // O region in float4s

    qsim_bcast<<<2048, 256, 0, stream>>>(d_in[1], d_in[2], (float*)d_out,
                                         n4A, n4B, F);
}

// Round 3
// 17.541 us; speedup vs baseline: 1.1292x; 1.1292x over previous
//
#include <hip/hip_runtime.h>
#include <math.h>

// 2-qubit circuit: output identical for every batch element (x only sets B).
// fp32 circuit on thread 0 (tolerance 2e-2; fp32 error ~1e-6), LDS broadcast,
// coalesced float4 stream-write.

struct C2f { float r, i; };

__device__ inline void rx_apply(C2f (&T)[4][2], int D, float th) {
    float s, c;
    __sincosf(th * 0.5f, &s, &c);   // fast path; accuracy ~1e-6, threshold 2e-2
    for (int d = 0; d < D; ++d) {
        C2f a = T[d][0], b = T[d][1];
        // M = [[c, -i s], [-i s, c]]
        T[d][0] = { c * a.r + s * b.i,  c * a.i - s * b.r };
        T[d][1] = { s * a.i + c * b.r, -s * a.r + c * b.i };
    }
}

__device__ inline void entangle2(C2f (&T0)[4][2], C2f (&T1)[4][2], int D) {
    for (int d = 0; d < D; ++d) {
        T0[D + d][0] = {0.0f, 0.0f};
        T0[D + d][1] = T0[d][1];
        T1[D + d][0] = T1[d][1];
        T1[D + d][1] = T1[d][0];
        T0[d][1] = {0.0f, 0.0f};
    }
}

// Harness normalizes f64 inputs to f32; fall back to f64 read if the f32
// interpretation looks insane (f64 pi's low word reads as 3.4e12 in f32).
__device__ inline void load_w(const void* p, float& a, float& b) {
    const float* f = (const float*)p;
    float f0 = f[0], f1 = f[1];
    bool sane = isfinite(f0) && isfinite(f1) && fabsf(f0) < 1e5f && fabsf(f1) < 1e5f;
    if (sane) { a = f0; b = f1; }
    else      { const double* d = (const double*)p; a = (float)d[0]; b = (float)d[1]; }
}

__global__ __launch_bounds__(256) void qsim_bcast(
        const void* __restrict__ w1p, const void* __restrict__ w2p,
        float* __restrict__ out, long long n4A, long long n4B, int F) {
    __shared__ float4 tbl[8];   // state pattern (4 float4s if F==1, 8 if F==2)
    __shared__ float4 otblS;    // O pattern

    if (threadIdx.x == 0) {
        float w1a, w1b, w2a, w2b;
        load_w(w1p, w1a, w1b);
        load_w(w2p, w2a, w2b);

        C2f T0[4][2], T1[4][2];
        for (int d = 0; d < 4; ++d)
            for (int j = 0; j < 2; ++j) { T0[d][j] = {0.f, 0.f}; T1[d][j] = {0.f, 0.f}; }
        T0[0][0] = {1.f, 0.f};
        T1[0][0] = {1.f, 0.f};

        rx_apply(T0, 1, w1a);
        rx_apply(T1, 1, w1b);
        entangle2(T0, T1, 1);
        rx_apply(T0, 2, w2a);
        rx_apply(T1, 2, w2b);
        entangle2(T0, T1, 2);

        // psi[i][j] = sum_d T0[d][i]*T1[d][j];  O = sum zz_ij |psi_ij|^2 (real)
        float O = 0.0f;
        const float zz[4] = {1.f, -1.f, -1.f, 1.f};
        for (int i2 = 0; i2 < 2; ++i2)
            for (int j2 = 0; j2 < 2; ++j2) {
                float pr = 0.f, pi = 0.f;
                for (int d = 0; d < 4; ++d) {
                    pr += T0[d][i2].r * T1[d][j2].r - T0[d][i2].i * T1[d][j2].i;
                    pi += T0[d][i2].r * T1[d][j2].i + T0[d][i2].i * T1[d][j2].r;
                }
                O += zz[i2 * 2 + j2] * (pr * pr + pi * pi);
            }

        // state flat order per batch: k = q*8 + d*2 + j  (16 complex values)
        float sv[32];  // interleaved re, im
        for (int d = 0; d < 4; ++d)
            for (int j = 0; j < 2; ++j) {
                int k0 = d * 2 + j;        // qubit 0
                int k1 = 8 + d * 2 + j;    // qubit 1
                sv[2 * k0]     = T0[d][j].r;
                sv[2 * k0 + 1] = T0[d][j].i;
                sv[2 * k1]     = T1[d][j].r;
                sv[2 * k1 + 1] = T1[d][j].i;
            }

        if (F == 1) {
            // real parts only: float f = Re(cplx[f%16]); tbl[p] covers floats 4p..4p+3
            for (int p = 0; p < 4; ++p)
                tbl[p] = make_float4(sv[8 * p + 0], sv[8 * p + 2], sv[8 * p + 4], sv[8 * p + 6]);
            otblS = make_float4(O, O, O, O);
        } else {
            // interleaved re/im: float f = sv[f%32]
            for (int p = 0; p < 8; ++p)
                tbl[p] = make_float4(sv[4 * p + 0], sv[4 * p + 1], sv[4 * p + 2], sv[4 * p + 3]);
            otblS = make_float4(O, 0.0f, O, 0.0f);
        }
    }
    __syncthreads();

    const int mask = 4 * F - 1;
    const long long total = n4A + n4B;
    float4* __restrict__ o4 = (float4*)out;
    const long long i0 = (long long)blockIdx.x * blockDim.x + threadIdx.x;
    const long long step = (long long)gridDim.x * blockDim.x;
    // step (524288) is a multiple of 8 float4s -> pattern index is loop-invariant
    const float4 va = tbl[(int)(i0 & mask)];
    const float4 vo = otblS;
    for (long long i = i0; i < total; i += step) {
        o4[i] = (i < n4A) ? va : vo;
    }
}

extern "C" void kernel_launch(void* const* d_in, const int* in_sizes, int n_in,
                              void* d_out, int out_size, void* d_ws, size_t ws_size,
                              hipStream_t stream) {
    const long long Bn = in_sizes[0];  // 500000 (x is (B,1))

    // Output = (state: B*16 cplx, O: B cplx), concatenated flat as float32.
    // F==1: real parts only  -> out_size = 17*B
    // F==2: re/im interleaved -> out_size = 34*B
    const int F = ((long long)out_size >= Bn * 34LL) ? 2 : 1;

    const long long n4A = Bn * 4LL * F;   // state region in float4s
    const long long n4B = (Bn * F) / 4LL; // O region in float4s

    qsim_bcast<<<2048, 256, 0, stream>>>(d_in[1], d_in[2], (float*)d_out,
                                         n4A, n4B, F);
}

// Round 5
// 12.334 us; speedup vs baseline: 1.6059x; 1.4222x over previous
//
#include <hip/hip_runtime.h>
#include <math.h>

// 2-qubit circuit: output identical for every batch element (x only sets B).
// Every thread computes the tiny circuit redundantly in registers (no LDS,
// no barrier), then stream-writes its loop-invariant float4 pattern with
// nontemporal stores.

typedef float f32x4 __attribute__((ext_vector_type(4)));

struct C2f { float r, i; };

__device__ inline void rx_apply(C2f (&T)[4][2], int D, float th) {
    float s, c;
    __sincosf(th * 0.5f, &s, &c);
    #pragma unroll
    for (int d = 0; d < 4; ++d) {
        if (d >= D) break;
        C2f a = T[d][0], b = T[d][1];
        // M = [[c, -i s], [-i s, c]]
        T[d][0] = { c * a.r + s * b.i,  c * a.i - s * b.r };
        T[d][1] = { s * a.i + c * b.r, -s * a.r + c * b.i };
    }
}

__device__ inline void entangle2(C2f (&T0)[4][2], C2f (&T1)[4][2], int D) {
    #pragma unroll
    for (int d = 0; d < 2; ++d) {
        if (d >= D) break;
        T0[D + d][0] = {0.0f, 0.0f};
        T0[D + d][1] = T0[d][1];
        T1[D + d][0] = T1[d][1];
        T1[D + d][1] = T1[d][0];
        T0[d][1] = {0.0f, 0.0f};
    }
}

// Harness normalizes f64 inputs to f32; fall back to f64 read if the f32
// interpretation looks insane (f64 pi's low word reads as 3.4e12 in f32).
__device__ inline void load_w(const void* p, float& a, float& b) {
    const float* f = (const float*)p;
    float f0 = f[0], f1 = f[1];
    bool sane = isfinite(f0) && isfinite(f1) && fabsf(f0) < 1e5f && fabsf(f1) < 1e5f;
    if (sane) { a = f0; b = f1; }
    else      { const double* d = (const double*)p; a = (float)d[0]; b = (float)d[1]; }
}

__device__ inline f32x4 mk4(float a, float b, float c, float d) {
    f32x4 v; v.x = a; v.y = b; v.z = c; v.w = d; return v;
}

__global__ __launch_bounds__(256) void qsim_bcast(
        const void* __restrict__ w1p, const void* __restrict__ w2p,
        float* __restrict__ out, long long n4A, long long n4B, int F) {
    float w1a, w1b, w2a, w2b;
    load_w(w1p, w1a, w1b);
    load_w(w2p, w2a, w2b);

    C2f T0[4][2], T1[4][2];
    #pragma unroll
    for (int d = 0; d < 4; ++d)
        #pragma unroll
        for (int j = 0; j < 2; ++j) { T0[d][j] = {0.f, 0.f}; T1[d][j] = {0.f, 0.f}; }
    T0[0][0] = {1.f, 0.f};
    T1[0][0] = {1.f, 0.f};

    rx_apply(T0, 1, w1a);
    rx_apply(T1, 1, w1b);
    entangle2(T0, T1, 1);
    rx_apply(T0, 2, w2a);
    rx_apply(T1, 2, w2b);
    entangle2(T0, T1, 2);

    // psi[i][j] = sum_d T0[d][i]*T1[d][j];  O = sum zz_ij |psi_ij|^2 (real)
    float O = 0.0f;
    #pragma unroll
    for (int i2 = 0; i2 < 2; ++i2)
        #pragma unroll
        for (int j2 = 0; j2 < 2; ++j2) {
            float pr = 0.f, pi = 0.f;
            #pragma unroll
            for (int d = 0; d < 4; ++d) {
                pr += T0[d][i2].r * T1[d][j2].r - T0[d][i2].i * T1[d][j2].i;
                pi += T0[d][i2].r * T1[d][j2].i + T0[d][i2].i * T1[d][j2].r;
            }
            float zz = ((i2 ^ j2) ? -1.f : 1.f);
            O += zz * (pr * pr + pi * pi);
        }

    // state flat order per batch: k = q*8 + d*2 + j  (16 complex values),
    // sv = interleaved re,im — all indices compile-time -> registers.
    float sv[32];
    #pragma unroll
    for (int d = 0; d < 4; ++d)
        #pragma unroll
        for (int j = 0; j < 2; ++j) {
            int k0 = d * 2 + j;        // qubit 0
            int k1 = 8 + d * 2 + j;    // qubit 1
            sv[2 * k0]     = T0[d][j].r;
            sv[2 * k0 + 1] = T0[d][j].i;
            sv[2 * k1]     = T1[d][j].r;
            sv[2 * k1 + 1] = T1[d][j].i;
        }

    const long long i0 = (long long)blockIdx.x * blockDim.x + threadIdx.x;
    const long long step = (long long)gridDim.x * blockDim.x;
    const int mask = 4 * F - 1;
    const int p = (int)(i0 & mask);

    // Uniform select tree over register candidates (no runtime-indexed array).
    f32x4 va, vo;
    if (F == 1) {
        f32x4 c0 = mk4(sv[0],  sv[2],  sv[4],  sv[6]);
        f32x4 c1 = mk4(sv[8],  sv[10], sv[12], sv[14]);
        f32x4 c2 = mk4(sv[16], sv[18], sv[20], sv[22]);
        f32x4 c3 = mk4(sv[24], sv[26], sv[28], sv[30]);
        va = (p < 2) ? (p == 0 ? c0 : c1) : (p == 2 ? c2 : c3);
        vo = mk4(O, O, O, O);
    } else {
        f32x4 c0 = mk4(sv[0],  sv[1],  sv[2],  sv[3]);
        f32x4 c1 = mk4(sv[4],  sv[5],  sv[6],  sv[7]);
        f32x4 c2 = mk4(sv[8],  sv[9],  sv[10], sv[11]);
        f32x4 c3 = mk4(sv[12], sv[13], sv[14], sv[15]);
        f32x4 c4 = mk4(sv[16], sv[17], sv[18], sv[19]);
        f32x4 c5 = mk4(sv[20], sv[21], sv[22], sv[23]);
        f32x4 c6 = mk4(sv[24], sv[25], sv[26], sv[27]);
        f32x4 c7 = mk4(sv[28], sv[29], sv[30], sv[31]);
        va = (p < 4) ? ((p < 2) ? (p == 0 ? c0 : c1) : (p == 2 ? c2 : c3))
                     : ((p < 6) ? (p == 4 ? c4 : c5) : (p == 6 ? c6 : c7));
        vo = mk4(O, 0.0f, O, 0.0f);
    }

    const long long total = n4A + n4B;
    f32x4* __restrict__ o4 = (f32x4*)out;
    long long i = i0;
    for (; i < n4A; i += step)
        __builtin_nontemporal_store(va, &o4[i]);
    for (; i < total; i += step)
        __builtin_nontemporal_store(vo, &o4[i]);
}

extern "C" void kernel_launch(void* const* d_in, const int* in_sizes, int n_in,
                              void* d_out, int out_size, void* d_ws, size_t ws_size,
                              hipStream_t stream) {
    const long long Bn = in_sizes[0];  // 500000 (x is (B,1))

    // Output = (state: B*16 cplx, O: B cplx), concatenated flat as float32.
    // F==1: real parts only  -> out_size = 17*B
    // F==2: re/im interleaved -> out_size = 34*B
    const int F = ((long long)out_size >= Bn * 34LL) ? 2 : 1;

    const long long n4A = Bn * 4LL * F;   // state region in float4s
    const long long n4B = (Bn * F) / 4LL; // O region in float4s

    qsim_bcast<<<2048, 256, 0, stream>>>(d_in[1], d_in[2], (float*)d_out,
                                         n4A, n4B, F);
}